// Round 20
// baseline (263.228 us; speedup 1.0000x reference)
//
#include <hip/hip_runtime.h>

typedef __attribute__((ext_vector_type(8))) short bf16x8;
typedef __attribute__((ext_vector_type(4))) float f32x4;
typedef __attribute__((ext_vector_type(16))) float f32x16;

#define MFMA16(a, b, c) __builtin_amdgcn_mfma_f32_16x16x32_bf16(a, b, c, 0, 0, 0)
#define MFMA32(a, b, c) __builtin_amdgcn_mfma_f32_32x32x16_bf16(a, b, c, 0, 0, 0)

__device__ __forceinline__ unsigned short f2bf(float f) {
    union { float f; unsigned u; } v; v.f = f;
    unsigned r = v.u + 0x7FFFu + ((v.u >> 16) & 1u);
    return (unsigned short)(r >> 16);
}
__device__ __forceinline__ float bf2f(unsigned short u) {
    union { unsigned u; float f; } v; v.u = ((unsigned)u) << 16;
    return v.f;
}

typedef __attribute__((address_space(1))) const unsigned char gas1;
typedef __attribute__((address_space(3))) unsigned char las3;
__device__ __forceinline__ void gload_lds16(const void* g, void* s) {
    __builtin_amdgcn_global_load_lds((gas1*)g, (las3*)s, 16, 0, 0);
}

// ---------------- X fp32 -> bf16 (vectorized) ----------------
__global__ void k_conv(const float* __restrict__ in, unsigned short* __restrict__ out, int n4) {
    int i = blockIdx.x * blockDim.x + threadIdx.x;
    if (i >= n4) return;
    float4 v = ((const float4*)in)[i];
    uint2 o;
    o.x = (unsigned)f2bf(v.x) | ((unsigned)f2bf(v.y) << 16);
    o.y = (unsigned)f2bf(v.z) | ((unsigned)f2bf(v.w) << 16);
    ((uint2*)out)[i] = o;
}

// ---------------- merged W transposes: fp32 [R=2048][C] -> bf16 [C][2048] ----------------
__global__ void k_transpose_all(const float* __restrict__ Wq, const float* __restrict__ Wk,
                                const float* __restrict__ Wv, const float* __restrict__ Wo,
                                unsigned short* __restrict__ Wt, unsigned short* __restrict__ Wot) {
    __shared__ float tile[32][33];
    int ry = blockIdx.x;
    int cy = blockIdx.y;
    const float* src; unsigned short* dst; int C; int ct;
    if (cy < 64)      { src = Wq; C = 2048; dst = Wt;                       ct = cy; }
    else if (cy < 72) { src = Wk; C = 256;  dst = Wt + (size_t)2048 * 2048; ct = cy - 64; }
    else if (cy < 80) { src = Wv; C = 256;  dst = Wt + (size_t)2304 * 2048; ct = cy - 72; }
    else              { src = Wo; C = 2048; dst = Wot;                      ct = cy - 80; }
    int tx = threadIdx.x, ty = threadIdx.y;
    #pragma unroll
    for (int j = 0; j < 32; j += 8)
        tile[ty + j][tx] = src[(size_t)(ry * 32 + ty + j) * C + ct * 32 + tx];
    __syncthreads();
    #pragma unroll
    for (int j = 0; j < 32; j += 8)
        dst[(size_t)(ct * 32 + ty + j) * 2048 + ry * 32 + tx] = f2bf(tile[tx][ty + j]);
}

// ============ 256x256-tile GEMM core (8 waves 4x2, 4-deep counted-vmcnt pipeline) ============
// Per K-step(32): stage A[256][32]+B[256][32] (32 x 1KB chunks, 4/wave); 12 ds_read_b128 +
// 32 MFMA per wave. vmcnt(8): own oldest group landed; barrier publishes all waves' groups.
#define G256_DECLS \
    __shared__ __align__(16) unsigned short As[4][256 * 32]; \
    __shared__ __align__(16) unsigned short Bs[4][256 * 32]; \
    int t = threadIdx.x, w = t >> 6, l = t & 63, g = l >> 4, lr = l & 15; \
    int wr = w >> 1, wc = w & 1; \
    f32x4 acc[4][8] = {}; \
    int c0 = w * 2, c1 = w * 2 + 1; \
    int srow0 = c0 * 16 + (l >> 2), srow1 = c1 * 16 + (l >> 2); \
    int scol = (l & 3) * 8; \
    const unsigned short* Ag0 = A + (size_t)(m0 + srow0) * 2048 + scol; \
    const unsigned short* Ag1 = A + (size_t)(m0 + srow1) * 2048 + scol; \
    const unsigned short* Bg0 = Bt + (size_t)(n0 + srow0) * 2048 + scol; \
    const unsigned short* Bg1 = Bt + (size_t)(n0 + srow1) * 2048 + scol; \
    int d0 = c0 * 512, d1 = c1 * 512;

#define G256_LOOP \
    _Pragma("unroll") \
    for (int p = 0; p < 3; ++p) { \
        gload_lds16(Ag0 + p * 32, As[p] + d0); \
        gload_lds16(Ag1 + p * 32, As[p] + d1); \
        gload_lds16(Bg0 + p * 32, Bs[p] + d0); \
        gload_lds16(Bg1 + p * 32, Bs[p] + d1); \
    } \
    for (int ks = 0; ks < 64; ++ks) { \
        if (ks < 62)       asm volatile("s_waitcnt vmcnt(8)" ::: "memory"); \
        else if (ks == 62) asm volatile("s_waitcnt vmcnt(4)" ::: "memory"); \
        else               asm volatile("s_waitcnt vmcnt(0)" ::: "memory"); \
        __builtin_amdgcn_s_barrier(); \
        if (ks + 3 < 64) { \
            int kk = (ks + 3) * 32, bb = (ks + 3) & 3; \
            gload_lds16(Ag0 + kk, As[bb] + d0); \
            gload_lds16(Ag1 + kk, As[bb] + d1); \
            gload_lds16(Bg0 + kk, Bs[bb] + d0); \
            gload_lds16(Bg1 + kk, Bs[bb] + d1); \
        } \
        const unsigned short* Ac = As[ks & 3]; \
        const unsigned short* Bc = Bs[ks & 3]; \
        bf16x8 af[4], bfr[8]; \
        _Pragma("unroll") \
        for (int mf = 0; mf < 4; ++mf) \
            af[mf] = *(const bf16x8*)(Ac + (wr * 64 + mf * 16 + lr) * 32 + g * 8); \
        _Pragma("unroll") \
        for (int nf = 0; nf < 8; ++nf) \
            bfr[nf] = *(const bf16x8*)(Bc + (wc * 128 + nf * 16 + lr) * 32 + g * 8); \
        __builtin_amdgcn_s_setprio(1); \
        _Pragma("unroll") \
        for (int mf = 0; mf < 4; ++mf) \
            _Pragma("unroll") \
            for (int nf = 0; nf < 8; ++nf) \
                acc[mf][nf] = MFMA16(af[mf], bfr[nf], acc[mf][nf]); \
        __builtin_amdgcn_s_setprio(0); \
    }

// ---------------- plain 256^2 GEMM (gemm2): C[M][N] fp32 ----------------
__global__ __launch_bounds__(512, 2) void k_gemm256(const unsigned short* __restrict__ A,
                                                    const unsigned short* __restrict__ Bt,
                                                    float* __restrict__ C, int N) {
    int m0 = blockIdx.y * 256, n0 = blockIdx.x * 256;
    G256_DECLS
    G256_LOOP
    #pragma unroll
    for (int mf = 0; mf < 4; ++mf)
        #pragma unroll
        for (int nf = 0; nf < 8; ++nf)
            #pragma unroll
            for (int r = 0; r < 4; ++r)
                C[(size_t)(m0 + wr * 64 + mf * 16 + g * 4 + r) * N + (n0 + wc * 128 + nf * 16 + lr)] = acc[mf][nf][r];
}

// ---------------- fused QKV 256^2 GEMM: bias + RoPE + direct Qb/Kb/Vtb layout ----------------
// grid (10, 16): n-tile covers heads {2nt, 2nt+1}; wave wc owns head 2nt+wc (128 cols).
__global__ __launch_bounds__(512, 2) void k_gemm_qkv(const unsigned short* __restrict__ A,
                                                     const unsigned short* __restrict__ Bt,
                                                     const float* __restrict__ bq,
                                                     const float* __restrict__ bk,
                                                     const float* __restrict__ bv,
                                                     const float* __restrict__ cosp,
                                                     const float* __restrict__ sinp,
                                                     unsigned short* __restrict__ Qb,
                                                     unsigned short* __restrict__ Kb,
                                                     unsigned short* __restrict__ Vtb) {
    const int S = 2048;
    int m0 = blockIdx.y * 256, n0 = blockIdx.x * 256;
    G256_DECLS
    G256_LOOP
    int hh = blockIdx.x * 2 + wc;    // head tile 0..19
    if (hh < 18) {
        const float* bias = (hh < 16) ? bq + hh * 128 : bk + (hh - 16) * 128;
        float scale = (hh < 16) ? 0.08838834764831845f : 1.0f;
        #pragma unroll
        for (int mf = 0; mf < 4; ++mf) {
            #pragma unroll
            for (int r = 0; r < 4; ++r) {
                int row = m0 + wr * 64 + mf * 16 + g * 4 + r;
                int b = row >> 11, s = row & 2047;
                const float* crow = cosp + (size_t)row * 128;
                const float* srow = sinp + (size_t)row * 128;
                unsigned short* orow = (hh < 16)
                    ? Qb + ((size_t)(b * 16 + hh) * S + s) * 128
                    : Kb + ((size_t)(b * 2 + (hh - 16)) * S + s) * 128;
                #pragma unroll
                for (int nf = 0; nf < 8; ++nf) {
                    int d = nf * 16 + lr;
                    float self = acc[mf][nf][r] + bias[d];
                    float rot = (nf < 4) ? -(acc[mf][nf + 4][r] + bias[d + 64])
                                         :  (acc[mf][nf - 4][r] + bias[d - 64]);
                    orow[d] = f2bf((self * crow[d] + rot * srow[d]) * scale);
                }
            }
        }
    } else {
        int kv = hh - 18;
        const float* bias = bv + kv * 128;
        #pragma unroll
        for (int mf = 0; mf < 4; ++mf) {
            int row0 = m0 + wr * 64 + mf * 16 + g * 4;
            int b = row0 >> 11, s0 = row0 & 2047;
            #pragma unroll
            for (int nf = 0; nf < 8; ++nf) {
                int d = nf * 16 + lr;
                float bb = bias[d];
                ushort4 pk;
                pk.x = f2bf(acc[mf][nf][0] + bb);
                pk.y = f2bf(acc[mf][nf][1] + bb);
                pk.z = f2bf(acc[mf][nf][2] + bb);
                pk.w = f2bf(acc[mf][nf][3] + bb);
                *(ushort4*)(Vtb + ((size_t)(b * 2 + kv) * 128 + d) * S + s0) = pk;
            }
        }
    }
}

// ---------------- flash attention v16 (unchanged): kv-split waves, uniform paired blocks ----
__global__ __launch_bounds__(256, 2) void k_attn(const unsigned short* __restrict__ Qb,
                                                 const unsigned short* __restrict__ Kb,
                                                 const unsigned short* __restrict__ Vt,
                                                 unsigned short* __restrict__ Ob) {
    const int S = 2048;
    __shared__ __align__(16) unsigned char LB[65536];
    unsigned short* Ks = (unsigned short*)LB;
    unsigned short* Vs = (unsigned short*)(LB + 32768);
    float* MF = (float*)LB;
    int bid = blockIdx.x;
    int G = bid & 31, p = bid >> 5;
    int kvg = G & 3, hsub = G >> 2;
    int b = kvg >> 1, kvh = kvg & 1, h = kvh * 8 + hsub;
    int t = threadIdx.x, w = t >> 6, l = t & 63;
    int l31 = l & 31, hi = l >> 5;
    int rh = w & 1, kh = w >> 1;
    const unsigned short* Kp = Kb + (size_t)(b * 2 + kvh) * S * 128;
    const unsigned short* Vp = Vt + (size_t)(b * 2 + kvh) * 128 * S;
    int koff[4], voff[4], ldst[4];
    #pragma unroll
    for (int jj = 0; jj < 4; ++jj) {
        int c = w * 4 + jj;
        int rk = c * 4 + (l >> 4);
        koff[jj] = rk * 128 + (((l & 15) ^ (rk & 15)) * 8);
        int rv = c * 8 + (l >> 3);
        voff[jj] = rv * S + (((l & 7) ^ (rv & 7)) * 8);
        ldst[jj] = c * 512;
    }
    int cur = 0;
    #pragma unroll
    for (int half = 0; half < 2; ++half) {
        int qt = half ? 31 - p : p;
        int qw = qt * 64 + rh * 32;
        int qrow = qw + l31;
        const unsigned short* Qrow = Qb + ((size_t)(b * 16 + h) * S + qrow) * 128;
        bf16x8 qfr[8];
        #pragma unroll
        for (int s = 0; s < 8; ++s)
            qfr[s] = *(const bf16x8*)(Qrow + s * 16 + hi * 8);
        f32x16 oacc[4] = {};
        float m_r = -3e38f, l_r = 0.f;
        int nkt = qt + 1;
        #pragma unroll
        for (int jj = 0; jj < 4; ++jj) {
            gload_lds16(Kp + koff[jj], Ks + cur * 8192 + ldst[jj]);
            gload_lds16(Vp + voff[jj], Vs + cur * 8192 + ldst[jj]);
        }
        for (int kt = 0; kt < nkt; ++kt) {
            int k0 = kt * 64;
            asm volatile("s_waitcnt vmcnt(0)" ::: "memory");
            __builtin_amdgcn_s_barrier();
            if (kt + 1 < nkt) {
                const unsigned short* kb = Kp + (size_t)(k0 + 64) * 128;
                const unsigned short* vb = Vp + (size_t)(k0 + 64);
                unsigned short* kd = Ks + (cur ^ 1) * 8192;
                unsigned short* vd = Vs + (cur ^ 1) * 8192;
                #pragma unroll
                for (int jj = 0; jj < 4; ++jj) {
                    gload_lds16(kb + koff[jj], kd + ldst[jj]);
                    gload_lds16(vb + voff[jj], vd + ldst[jj]);
                }
            }
            const unsigned short* Kc = Ks + cur * 8192;
            const unsigned short* Vc = Vs + cur * 8192;
            int kbase = kh * 32;
            bool active = (k0 + kbase <= qw + 31);
            if (active) {
                f32x16 s0v = {};
                __builtin_amdgcn_s_setprio(1);
                #pragma unroll
                for (int s = 0; s < 8; ++s) {
                    int sl = ((s * 2 + hi) ^ (l31 & 15)) * 8;
                    bf16x8 ka = *(const bf16x8*)(Kc + (kbase + l31) * 128 + sl);
                    s0v = MFMA32(ka, qfr[s], s0v);
                }
                __builtin_amdgcn_s_setprio(0);
                if (k0 + kbase + 31 > qw) {
                    #pragma unroll
                    for (int e = 0; e < 16; ++e) {
                        int off = (e & 3) + 8 * (e >> 2) + 4 * hi;
                        if (k0 + kbase + off > qrow) s0v[e] = -1e30f;
                    }
                }
                float mv[16];
                #pragma unroll
                for (int e = 0; e < 16; ++e) mv[e] = s0v[e];
                #pragma unroll
                for (int st = 8; st >= 1; st >>= 1)
                    #pragma unroll
                    for (int e = 0; e < 8; ++e)
                        if (e < st) mv[e] = fmaxf(mv[e], mv[e + st]);
                float mx = fmaxf(mv[0], __shfl_xor(mv[0], 32));
                float mnew = fmaxf(m_r, mx);
                float alpha = __expf(m_r - mnew);
                m_r = mnew;
                float ps = 0.f;
                #pragma unroll
                for (int e = 0; e < 16; ++e) {
                    s0v[e] = __expf(s0v[e] - mnew); ps += s0v[e];
                }
                l_r = l_r * alpha + ps;
                #pragma unroll
                for (int m = 0; m < 4; ++m)
                    #pragma unroll
                    for (int e = 0; e < 16; ++e) oacc[m][e] *= alpha;
                bf16x8 pf[2];
                union FU { unsigned u[4]; bf16x8 v; };
                #pragma unroll
                for (int g2 = 0; g2 < 2; ++g2) {
                    int base = g2 * 8;
                    unsigned w0 = (unsigned)f2bf(s0v[base+0]) | ((unsigned)f2bf(s0v[base+1]) << 16);
                    unsigned w1 = (unsigned)f2bf(s0v[base+2]) | ((unsigned)f2bf(s0v[base+3]) << 16);
                    unsigned w2 = (unsigned)f2bf(s0v[base+4]) | ((unsigned)f2bf(s0v[base+5]) << 16);
                    unsigned w3 = (unsigned)f2bf(s0v[base+6]) | ((unsigned)f2bf(s0v[base+7]) << 16);
                    unsigned p0 = (unsigned)__shfl_xor((int)w0, 32);
                    unsigned p1 = (unsigned)__shfl_xor((int)w1, 32);
                    unsigned p2 = (unsigned)__shfl_xor((int)w2, 32);
                    unsigned p3 = (unsigned)__shfl_xor((int)w3, 32);
                    FU f;
                    if (hi == 0) { f.u[0] = w0; f.u[1] = w1; f.u[2] = p0; f.u[3] = p1; }
                    else         { f.u[0] = p2; f.u[1] = p3; f.u[2] = w2; f.u[3] = w3; }
                    pf[g2] = f.v;
                }
                __builtin_amdgcn_s_setprio(1);
                #pragma unroll
                for (int m = 0; m < 4; ++m) {
                    #pragma unroll
                    for (int s = 0; s < 2; ++s) {
                        int sl = ((kh * 4 + s * 2 + hi) ^ (l31 & 7)) * 8;
                        bf16x8 va = *(const bf16x8*)(Vc + (m * 32 + l31) * 64 + sl);
                        oacc[m] = MFMA32(va, pf[s], oacc[m]);
                    }
                }
                __builtin_amdgcn_s_setprio(0);
            }
            cur ^= 1;
        }
        __syncthreads();
        if (kh == 1) {
            float* mb = MF + (size_t)(rh * 64 + l) * 66;
            #pragma unroll
            for (int m = 0; m < 4; ++m)
                #pragma unroll
                for (int e = 0; e < 16; ++e) mb[m * 16 + e] = oacc[m][e];
            mb[64] = m_r;
            mb[65] = l_r;
        }
        __syncthreads();
        if (kh == 0) {
            const float* mb = MF + (size_t)(rh * 64 + l) * 66;
            float m2 = mb[64], l2 = mb[65];
            float mnew = fmaxf(m_r, m2);
            float a1 = __expf(m_r - mnew), a2 = __expf(m2 - mnew);
            l_r = l_r * a1 + l2 * a2;
            #pragma unroll
            for (int m = 0; m < 4; ++m)
                #pragma unroll
                for (int e = 0; e < 16; ++e)
                    oacc[m][e] = oacc[m][e] * a1 + mb[m * 16 + e] * a2;
            float inv = 1.0f / (l_r + __shfl_xor(l_r, 32));
            unsigned short* orp = Ob + ((size_t)b * S + qrow) * 2048 + h * 128;
            #pragma unroll
            for (int m = 0; m < 4; ++m)
                #pragma unroll
                for (int rg = 0; rg < 4; ++rg) {
                    int dvb = m * 32 + 8 * rg + 4 * hi;
                    uint2 st;
                    st.x = (unsigned)f2bf(oacc[m][rg * 4 + 0] * inv)
                         | ((unsigned)f2bf(oacc[m][rg * 4 + 1] * inv) << 16);
                    st.y = (unsigned)f2bf(oacc[m][rg * 4 + 2] * inv)
                         | ((unsigned)f2bf(oacc[m][rg * 4 + 3] * inv) << 16);
                    *(uint2*)(orp + dvb) = st;
                }
        }
        __syncthreads();
    }
}

extern "C" void kernel_launch(void* const* d_in, const int* in_sizes, int n_in,
                              void* d_out, int out_size, void* d_ws, size_t ws_size,
                              hipStream_t stream) {
    const float* X    = (const float*)d_in[0];
    const float* cosp = (const float*)d_in[1];
    const float* sinp = (const float*)d_in[2];
    // d_in[3] = attention_mask (exactly causal; implemented analytically)
    const float* Wq = (const float*)d_in[4];
    const float* bq = (const float*)d_in[5];
    const float* Wk = (const float*)d_in[6];
    const float* bk = (const float*)d_in[7];
    const float* Wv = (const float*)d_in[8];
    const float* bv = (const float*)d_in[9];
    const float* Wo = (const float*)d_in[10];
    float* Out = (float*)d_out;

    char* ws = (char*)d_ws;
    unsigned short* Xb  = (unsigned short*)(ws + 0);
    unsigned short* Wt  = (unsigned short*)(ws + 16777216);
    unsigned short* Wot = (unsigned short*)(ws + 27262976);
    unsigned short* Qb  = (unsigned short*)(ws + 35651584);   // 16 MB
    unsigned short* Kb  = (unsigned short*)(ws + 52428800);   // 2 MB
    unsigned short* Vtb = (unsigned short*)(ws + 54525952);   // 2 MB
    unsigned short* Ab  = (unsigned short*)(ws + 56623104);   // 16 MB

    k_conv<<<2097152 / 256, 256, 0, stream>>>(X, Xb, 2097152);
    k_transpose_all<<<dim3(64, 144), dim3(32, 8), 0, stream>>>(Wq, Wk, Wv, Wo, Wt, Wot);
    k_gemm_qkv<<<dim3(10, 16), 512, 0, stream>>>(Xb, Wt, bq, bk, bv, cosp, sinp, Qb, Kb, Vtb);
    k_attn<<<dim3(512), 256, 0, stream>>>(Qb, Kb, Vtb, Ab);
    k_gemm256<<<dim3(8, 16), 512, 0, stream>>>(Ab, Wot, Out, 2048);
}

// Round 21
// 228.717 us; speedup vs baseline: 1.1509x; 1.1509x over previous
//
#include <hip/hip_runtime.h>

typedef __attribute__((ext_vector_type(8))) short bf16x8;
typedef __attribute__((ext_vector_type(4))) float f32x4;
typedef __attribute__((ext_vector_type(16))) float f32x16;

#define MFMA16(a, b, c) __builtin_amdgcn_mfma_f32_16x16x32_bf16(a, b, c, 0, 0, 0)
#define MFMA32(a, b, c) __builtin_amdgcn_mfma_f32_32x32x16_bf16(a, b, c, 0, 0, 0)

__device__ __forceinline__ unsigned short f2bf(float f) {
    union { float f; unsigned u; } v; v.f = f;
    unsigned r = v.u + 0x7FFFu + ((v.u >> 16) & 1u);
    return (unsigned short)(r >> 16);
}
__device__ __forceinline__ float bf2f(unsigned short u) {
    union { unsigned u; float f; } v; v.u = ((unsigned)u) << 16;
    return v.f;
}

typedef __attribute__((address_space(1))) const unsigned char gas1;
typedef __attribute__((address_space(3))) unsigned char las3;
__device__ __forceinline__ void gload_lds16(const void* g, void* s) {
    __builtin_amdgcn_global_load_lds((gas1*)g, (las3*)s, 16, 0, 0);
}

// ---------------- X fp32 -> bf16 (vectorized) ----------------
__global__ void k_conv(const float* __restrict__ in, unsigned short* __restrict__ out, int n4) {
    int i = blockIdx.x * blockDim.x + threadIdx.x;
    if (i >= n4) return;
    float4 v = ((const float4*)in)[i];
    uint2 o;
    o.x = (unsigned)f2bf(v.x) | ((unsigned)f2bf(v.y) << 16);
    o.y = (unsigned)f2bf(v.z) | ((unsigned)f2bf(v.w) << 16);
    ((uint2*)out)[i] = o;
}

// ---------------- merged W transposes: fp32 [R=2048][C] -> bf16 [C][2048] ----------------
__global__ void k_transpose_all(const float* __restrict__ Wq, const float* __restrict__ Wk,
                                const float* __restrict__ Wv, const float* __restrict__ Wo,
                                unsigned short* __restrict__ Wt, unsigned short* __restrict__ Wot) {
    __shared__ float tile[32][33];
    int ry = blockIdx.x;
    int cy = blockIdx.y;
    const float* src; unsigned short* dst; int C; int ct;
    if (cy < 64)      { src = Wq; C = 2048; dst = Wt;                       ct = cy; }
    else if (cy < 72) { src = Wk; C = 256;  dst = Wt + (size_t)2048 * 2048; ct = cy - 64; }
    else if (cy < 80) { src = Wv; C = 256;  dst = Wt + (size_t)2304 * 2048; ct = cy - 72; }
    else              { src = Wo; C = 2048; dst = Wot;                      ct = cy - 80; }
    int tx = threadIdx.x, ty = threadIdx.y;
    #pragma unroll
    for (int j = 0; j < 32; j += 8)
        tile[ty + j][tx] = src[(size_t)(ry * 32 + ty + j) * C + ct * 32 + tx];
    __syncthreads();
    #pragma unroll
    for (int j = 0; j < 32; j += 8)
        dst[(size_t)(ct * 32 + ty + j) * 2048 + ry * 32 + tx] = f2bf(tile[tx][ty + j]);
}

// ---------------- GEMM, 2-phase pipelined (attn-style single-barrier dbuf) ----------------
__global__ __launch_bounds__(256) void k_gemm(const unsigned short* __restrict__ A,
                                              const unsigned short* __restrict__ Bt,
                                              float* __restrict__ C, int M, int N, int K) {
    __shared__ __align__(16) unsigned short As[2][128 * 32];
    __shared__ __align__(16) unsigned short Bs[2][128 * 32];
    int t = threadIdx.x, w = t >> 6, l = t & 63, g = l >> 4, lr = l & 15;
    int m0 = blockIdx.y * 128, n0 = blockIdx.x * 128;
    int wm = (w >> 1) * 64, wn = (w & 1) * 64;
    f32x4 acc[4][4] = {};
    int c0 = w * 2, c1 = w * 2 + 1;
    int srow0 = c0 * 16 + (l >> 2), srow1 = c1 * 16 + (l >> 2);
    int scol = (l & 3) * 8;
    const unsigned short* Ag0 = A + (size_t)(m0 + srow0) * K + scol;
    const unsigned short* Ag1 = A + (size_t)(m0 + srow1) * K + scol;
    const unsigned short* Bg0 = Bt + (size_t)(n0 + srow0) * K + scol;
    const unsigned short* Bg1 = Bt + (size_t)(n0 + srow1) * K + scol;
    int d0 = c0 * 512, d1 = c1 * 512;
    gload_lds16(Ag0, As[0] + d0);
    gload_lds16(Ag1, As[0] + d1);
    gload_lds16(Bg0, Bs[0] + d0);
    gload_lds16(Bg1, Bs[0] + d1);
    int cur = 0;
    for (int k0 = 0; k0 < K; k0 += 32) {
        asm volatile("s_waitcnt vmcnt(0)" ::: "memory");
        __builtin_amdgcn_s_barrier();
        if (k0 + 32 < K) {
            gload_lds16(Ag0 + k0 + 32, As[cur ^ 1] + d0);
            gload_lds16(Ag1 + k0 + 32, As[cur ^ 1] + d1);
            gload_lds16(Bg0 + k0 + 32, Bs[cur ^ 1] + d0);
            gload_lds16(Bg1 + k0 + 32, Bs[cur ^ 1] + d1);
        }
        bf16x8 af[4], bfr[4];
        #pragma unroll
        for (int f = 0; f < 4; ++f) {
            af[f] = *(const bf16x8*)(As[cur] + (wm + f * 16 + lr) * 32 + g * 8);
            bfr[f] = *(const bf16x8*)(Bs[cur] + (wn + f * 16 + lr) * 32 + g * 8);
        }
        __builtin_amdgcn_s_setprio(1);
        #pragma unroll
        for (int mf = 0; mf < 4; ++mf)
            #pragma unroll
            for (int nf = 0; nf < 4; ++nf)
                acc[mf][nf] = MFMA16(af[mf], bfr[nf], acc[mf][nf]);
        __builtin_amdgcn_s_setprio(0);
        cur ^= 1;
    }
    #pragma unroll
    for (int mf = 0; mf < 4; ++mf)
        #pragma unroll
        for (int nf = 0; nf < 4; ++nf)
            #pragma unroll
            for (int r = 0; r < 4; ++r)
                C[(size_t)(m0 + wm + mf * 16 + g * 4 + r) * N + (n0 + wn + nf * 16 + lr)] = acc[mf][nf][r];
}

// ---------------- fused QKV GEMM, 2-phase pipelined; grid (20 heads, 32 m-tiles) ----------
__global__ __launch_bounds__(256) void k_gemm_qkv(const unsigned short* __restrict__ A,
                                                  const unsigned short* __restrict__ Bt,
                                                  const float* __restrict__ bq,
                                                  const float* __restrict__ bk,
                                                  const float* __restrict__ bv,
                                                  const float* __restrict__ cosp,
                                                  const float* __restrict__ sinp,
                                                  unsigned short* __restrict__ Qb,
                                                  unsigned short* __restrict__ Kb,
                                                  unsigned short* __restrict__ Vtb) {
    const int K = 2048, S = 2048;
    __shared__ __align__(16) unsigned short As[2][128 * 32];
    __shared__ __align__(16) unsigned short Bs[2][128 * 32];
    int t = threadIdx.x, w = t >> 6, l = t & 63, g = l >> 4, lr = l & 15;
    int hh = blockIdx.x, m0 = blockIdx.y * 128, n0 = hh * 128;
    f32x4 acc[2][8] = {};
    int c0 = w * 2, c1 = w * 2 + 1;
    int srow0 = c0 * 16 + (l >> 2), srow1 = c1 * 16 + (l >> 2);
    int scol = (l & 3) * 8;
    const unsigned short* Ag0 = A + (size_t)(m0 + srow0) * K + scol;
    const unsigned short* Ag1 = A + (size_t)(m0 + srow1) * K + scol;
    const unsigned short* Bg0 = Bt + (size_t)(n0 + srow0) * K + scol;
    const unsigned short* Bg1 = Bt + (size_t)(n0 + srow1) * K + scol;
    int d0 = c0 * 512, d1 = c1 * 512;
    gload_lds16(Ag0, As[0] + d0);
    gload_lds16(Ag1, As[0] + d1);
    gload_lds16(Bg0, Bs[0] + d0);
    gload_lds16(Bg1, Bs[0] + d1);
    int cur = 0;
    for (int k0 = 0; k0 < K; k0 += 32) {
        asm volatile("s_waitcnt vmcnt(0)" ::: "memory");
        __builtin_amdgcn_s_barrier();
        if (k0 + 32 < K) {
            gload_lds16(Ag0 + k0 + 32, As[cur ^ 1] + d0);
            gload_lds16(Ag1 + k0 + 32, As[cur ^ 1] + d1);
            gload_lds16(Bg0 + k0 + 32, Bs[cur ^ 1] + d0);
            gload_lds16(Bg1 + k0 + 32, Bs[cur ^ 1] + d1);
        }
        bf16x8 af[2], bfr[8];
        #pragma unroll
        for (int f = 0; f < 2; ++f)
            af[f] = *(const bf16x8*)(As[cur] + (w * 32 + f * 16 + lr) * 32 + g * 8);
        #pragma unroll
        for (int f = 0; f < 8; ++f)
            bfr[f] = *(const bf16x8*)(Bs[cur] + (f * 16 + lr) * 32 + g * 8);
        __builtin_amdgcn_s_setprio(1);
        #pragma unroll
        for (int mf = 0; mf < 2; ++mf)
            #pragma unroll
            for (int nf = 0; nf < 8; ++nf)
                acc[mf][nf] = MFMA16(af[mf], bfr[nf], acc[mf][nf]);
        __builtin_amdgcn_s_setprio(0);
        cur ^= 1;
    }
    // ---- fused epilogue ----
    if (hh < 18) {
        const float* bias = (hh < 16) ? bq + hh * 128 : bk + (hh - 16) * 128;
        float scale = (hh < 16) ? 0.08838834764831845f : 1.0f;
        #pragma unroll
        for (int mf = 0; mf < 2; ++mf) {
            #pragma unroll
            for (int r = 0; r < 4; ++r) {
                int row = m0 + w * 32 + mf * 16 + g * 4 + r;
                int b = row >> 11, s = row & 2047;
                const float* crow = cosp + (size_t)row * 128;
                const float* srow = sinp + (size_t)row * 128;
                unsigned short* orow = (hh < 16)
                    ? Qb + ((size_t)(b * 16 + hh) * S + s) * 128
                    : Kb + ((size_t)(b * 2 + (hh - 16)) * S + s) * 128;
                #pragma unroll
                for (int nf = 0; nf < 8; ++nf) {
                    int d = nf * 16 + lr;
                    float self = acc[mf][nf][r] + bias[d];
                    float rot = (nf < 4) ? -(acc[mf][nf + 4][r] + bias[d + 64])
                                         :  (acc[mf][nf - 4][r] + bias[d - 64]);
                    orow[d] = f2bf((self * crow[d] + rot * srow[d]) * scale);
                }
            }
        }
    } else {
        int kv = hh - 18;
        const float* bias = bv + kv * 128;
        #pragma unroll
        for (int mf = 0; mf < 2; ++mf) {
            int row0 = m0 + w * 32 + mf * 16 + g * 4;
            int b = row0 >> 11, s0 = row0 & 2047;
            #pragma unroll
            for (int nf = 0; nf < 8; ++nf) {
                int d = nf * 16 + lr;
                float bb = bias[d];
                ushort4 pk;
                pk.x = f2bf(acc[mf][nf][0] + bb);
                pk.y = f2bf(acc[mf][nf][1] + bb);
                pk.z = f2bf(acc[mf][nf][2] + bb);
                pk.w = f2bf(acc[mf][nf][3] + bb);
                *(ushort4*)(Vtb + ((size_t)(b * 2 + kv) * 128 + d) * S + s0) = pk;
            }
        }
    }
}

// ---------------- flash attention v17: v16 + defer-max (T13, THR=8) ----------------
__global__ __launch_bounds__(256, 2) void k_attn(const unsigned short* __restrict__ Qb,
                                                 const unsigned short* __restrict__ Kb,
                                                 const unsigned short* __restrict__ Vt,
                                                 unsigned short* __restrict__ Ob) {
    const int S = 2048;
    __shared__ __align__(16) unsigned char LB[65536];
    unsigned short* Ks = (unsigned short*)LB;            // [2][64][128] 32 KB dbuf
    unsigned short* Vs = (unsigned short*)(LB + 32768);  // [2][128][64] 32 KB dbuf
    float* MF = (float*)LB;                              // merge overlay (loop-dead)
    int bid = blockIdx.x;
    int G = bid & 31, p = bid >> 5;
    int kvg = G & 3, hsub = G >> 2;
    int b = kvg >> 1, kvh = kvg & 1, h = kvh * 8 + hsub;
    int t = threadIdx.x, w = t >> 6, l = t & 63;
    int l31 = l & 31, hi = l >> 5;
    int rh = w & 1, kh = w >> 1;
    const unsigned short* Kp = Kb + (size_t)(b * 2 + kvh) * S * 128;
    const unsigned short* Vp = Vt + (size_t)(b * 2 + kvh) * 128 * S;
    int koff[4], voff[4], ldst[4];
    #pragma unroll
    for (int jj = 0; jj < 4; ++jj) {
        int c = w * 4 + jj;
        int rk = c * 4 + (l >> 4);
        koff[jj] = rk * 128 + (((l & 15) ^ (rk & 15)) * 8);
        int rv = c * 8 + (l >> 3);
        voff[jj] = rv * S + (((l & 7) ^ (rv & 7)) * 8);
        ldst[jj] = c * 512;
    }
    int cur = 0;
    #pragma unroll
    for (int half = 0; half < 2; ++half) {
        int qt = half ? 31 - p : p;
        int qw = qt * 64 + rh * 32;
        int qrow = qw + l31;
        const unsigned short* Qrow = Qb + ((size_t)(b * 16 + h) * S + qrow) * 128;
        bf16x8 qfr[8];
        #pragma unroll
        for (int s = 0; s < 8; ++s)
            qfr[s] = *(const bf16x8*)(Qrow + s * 16 + hi * 8);
        f32x16 oacc[4] = {};
        float m_r = -3e38f, l_r = 0.f;
        int nkt = qt + 1;
        #pragma unroll
        for (int jj = 0; jj < 4; ++jj) {
            gload_lds16(Kp + koff[jj], Ks + cur * 8192 + ldst[jj]);
            gload_lds16(Vp + voff[jj], Vs + cur * 8192 + ldst[jj]);
        }
        for (int kt = 0; kt < nkt; ++kt) {
            int k0 = kt * 64;
            asm volatile("s_waitcnt vmcnt(0)" ::: "memory");
            __builtin_amdgcn_s_barrier();
            if (kt + 1 < nkt) {
                const unsigned short* kb = Kp + (size_t)(k0 + 64) * 128;
                const unsigned short* vb = Vp + (size_t)(k0 + 64);
                unsigned short* kd = Ks + (cur ^ 1) * 8192;
                unsigned short* vd = Vs + (cur ^ 1) * 8192;
                #pragma unroll
                for (int jj = 0; jj < 4; ++jj) {
                    gload_lds16(kb + koff[jj], kd + ldst[jj]);
                    gload_lds16(vb + voff[jj], vd + ldst[jj]);
                }
            }
            const unsigned short* Kc = Ks + cur * 8192;
            const unsigned short* Vc = Vs + cur * 8192;
            int kbase = kh * 32;
            bool active = (k0 + kbase <= qw + 31);
            if (active) {
                f32x16 s0v = {};
                __builtin_amdgcn_s_setprio(1);
                #pragma unroll
                for (int s = 0; s < 8; ++s) {
                    int sl = ((s * 2 + hi) ^ (l31 & 15)) * 8;
                    bf16x8 ka = *(const bf16x8*)(Kc + (kbase + l31) * 128 + sl);
                    s0v = MFMA32(ka, qfr[s], s0v);
                }
                __builtin_amdgcn_s_setprio(0);
                if (k0 + kbase + 31 > qw) {
                    #pragma unroll
                    for (int e = 0; e < 16; ++e) {
                        int off = (e & 3) + 8 * (e >> 2) + 4 * hi;
                        if (k0 + kbase + off > qrow) s0v[e] = -1e30f;
                    }
                }
                float mv[16];
                #pragma unroll
                for (int e = 0; e < 16; ++e) mv[e] = s0v[e];
                #pragma unroll
                for (int st = 8; st >= 1; st >>= 1)
                    #pragma unroll
                    for (int e = 0; e < 8; ++e)
                        if (e < st) mv[e] = fmaxf(mv[e], mv[e + st]);
                float mx = fmaxf(mv[0], __shfl_xor(mv[0], 32));
                // ---- defer-max (T13): rescale only if the max grew by > 8 ----
                if (__any(mx > m_r + 8.0f)) {
                    float mnew = fmaxf(m_r, mx);
                    float alpha = __expf(m_r - mnew);
                    m_r = mnew;
                    l_r *= alpha;
                    #pragma unroll
                    for (int m = 0; m < 4; ++m)
                        #pragma unroll
                        for (int e = 0; e < 16; ++e) oacc[m][e] *= alpha;
                }
                float ps = 0.f;
                #pragma unroll
                for (int e = 0; e < 16; ++e) {
                    s0v[e] = __expf(s0v[e] - m_r); ps += s0v[e];
                    s1v_unused:;
                }
                l_r += ps;
                bf16x8 pf[2];
                union FU { unsigned u[4]; bf16x8 v; };
                #pragma unroll
                for (int g2 = 0; g2 < 2; ++g2) {
                    int base = g2 * 8;
                    unsigned w0 = (unsigned)f2bf(s0v[base+0]) | ((unsigned)f2bf(s0v[base+1]) << 16);
                    unsigned w1 = (unsigned)f2bf(s0v[base+2]) | ((unsigned)f2bf(s0v[base+3]) << 16);
                    unsigned w2 = (unsigned)f2bf(s0v[base+4]) | ((unsigned)f2bf(s0v[base+5]) << 16);
                    unsigned w3 = (unsigned)f2bf(s0v[base+6]) | ((unsigned)f2bf(s0v[base+7]) << 16);
                    unsigned p0 = (unsigned)__shfl_xor((int)w0, 32);
                    unsigned p1 = (unsigned)__shfl_xor((int)w1, 32);
                    unsigned p2 = (unsigned)__shfl_xor((int)w2, 32);
                    unsigned p3 = (unsigned)__shfl_xor((int)w3, 32);
                    FU f;
                    if (hi == 0) { f.u[0] = w0; f.u[1] = w1; f.u[2] = p0; f.u[3] = p1; }
                    else         { f.u[0] = p2; f.u[1] = p3; f.u[2] = w2; f.u[3] = w3; }
                    pf[g2] = f.v;
                }
                __builtin_amdgcn_s_setprio(1);
                #pragma unroll
                for (int m = 0; m < 4; ++m) {
                    #pragma unroll
                    for (int s = 0; s < 2; ++s) {
                        int sl = ((kh * 4 + s * 2 + hi) ^ (l31 & 7)) * 8;
                        bf16x8 va = *(const bf16x8*)(Vc + (m * 32 + l31) * 64 + sl);
                        oacc[m] = MFMA32(va, pf[s], oacc[m]);
                    }
                }
                __builtin_amdgcn_s_setprio(0);
            }
            cur ^= 1;
        }
        __syncthreads();
        if (kh == 1) {
            float* mb = MF + (size_t)(rh * 64 + l) * 66;
            #pragma unroll
            for (int m = 0; m < 4; ++m)
                #pragma unroll
                for (int e = 0; e < 16; ++e) mb[m * 16 + e] = oacc[m][e];
            mb[64] = m_r;
            mb[65] = l_r;
        }
        __syncthreads();
        if (kh == 0) {
            const float* mb = MF + (size_t)(rh * 64 + l) * 66;
            float m2 = mb[64], l2 = mb[65];
            float mnew = fmaxf(m_r, m2);
            float a1 = __expf(m_r - mnew), a2 = __expf(m2 - mnew);
            l_r = l_r * a1 + l2 * a2;
            #pragma unroll
            for (int m = 0; m < 4; ++m)
                #pragma unroll
                for (int e = 0; e < 16; ++e)
                    oacc[m][e] = oacc[m][e] * a1 + mb[m * 16 + e] * a2;
            float inv = 1.0f / (l_r + __shfl_xor(l_r, 32));
            unsigned short* orp = Ob + ((size_t)b * S + qrow) * 2048 + h * 128;
            #pragma unroll
            for (int m = 0; m < 4; ++m)
                #pragma unroll
                for (int rg = 0; rg < 4; ++rg) {
                    int dvb = m * 32 + 8 * rg + 4 * hi;
                    uint2 st;
                    st.x = (unsigned)f2bf(oacc[m][rg * 4 + 0] * inv)
                         | ((unsigned)f2bf(oacc[m][rg * 4 + 1] * inv) << 16);
                    st.y = (unsigned)f2bf(oacc[m][rg * 4 + 2] * inv)
                         | ((unsigned)f2bf(oacc[m][rg * 4 + 3] * inv) << 16);
                    *(uint2*)(orp + dvb) = st;
                }
        }
        __syncthreads();
    }
}

extern "C" void kernel_launch(void* const* d_in, const int* in_sizes, int n_in,
                              void* d_out, int out_size, void* d_ws, size_t ws_size,
                              hipStream_t stream) {
    const float* X    = (const float*)d_in[0];
    const float* cosp = (const float*)d_in[1];
    const float* sinp = (const float*)d_in[2];
    // d_in[3] = attention_mask (exactly causal; implemented analytically)
    const float* Wq = (const float*)d_in[4];
    const float* bq = (const float*)d_in[5];
    const float* Wk = (const float*)d_in[6];
    const float* bk = (const float*)d_in[7];
    const float* Wv = (const float*)d_in[8];
    const float* bv = (const float*)d_in[9];
    const float* Wo = (const float*)d_in[10];
    float* Out = (float*)d_out;

    char* ws = (char*)d_ws;
    unsigned short* Xb  = (unsigned short*)(ws + 0);
    unsigned short* Wt  = (unsigned short*)(ws + 16777216);
    unsigned short* Wot = (unsigned short*)(ws + 27262976);
    unsigned short* Qb  = (unsigned short*)(ws + 35651584);   // 16 MB
    unsigned short* Kb  = (unsigned short*)(ws + 52428800);   // 2 MB
    unsigned short* Vtb = (unsigned short*)(ws + 54525952);   // 2 MB
    unsigned short* Ab  = (unsigned short*)(ws + 56623104);   // 16 MB

    k_conv<<<2097152 / 256, 256, 0, stream>>>(X, Xb, 2097152);
    k_transpose_all<<<dim3(64, 144), dim3(32, 8), 0, stream>>>(Wq, Wk, Wv, Wo, Wt, Wot);
    k_gemm_qkv<<<dim3(20, 32), 256, 0, stream>>>(Xb, Wt, bq, bk, bv, cosp, sinp, Qb, Kb, Vtb);
    k_attn<<<dim3(512), 256, 0, stream>>>(Qb, Kb, Vtb, Ab);
    k_gemm<<<dim3(16, 32), 256, 0, stream>>>(Ab, Wot, Out, 4096, 2048, 2048);
}